// Round 1
// baseline (92.357 us; speedup 1.0000x reference)
//
#include <hip/hip_runtime.h>
#include <hip/hip_bf16.h>
#include <math.h>

#define NFEAT 16
#define NRULE 64
#define RSTRIDE 64   // floats per rule block in the packed constant buffer

// Packed constant layout per rule r (floats, base = cst + r*RSTRIDE):
//   [0:16)  negc[a]  = -1/(2*sigma^2)
//   [16:32) cmu2[a]  =  2*mu/(2*sigma^2) = mu/sigma^2
//   [32:48) rho_a[a] =  rho[r][a]
//   [48]    bias     =  rho[r][A]
//   [49]    K        = -sum_a mu^2/(2*sigma^2)

__global__ void fuzzy_prep(const float* __restrict__ mu,
                           const float* __restrict__ sigma,
                           const float* __restrict__ rho,
                           float* __restrict__ cst) {
    int r = threadIdx.x;
    if (r >= NRULE) return;
    float* c = cst + r * RSTRIDE;
    float K = 0.0f;
#pragma unroll
    for (int a = 0; a < NFEAT; ++a) {
        float m = mu[r * NFEAT + a];
        float s = sigma[r * NFEAT + a];
        float inv = 1.0f / (2.0f * s * s);
        c[a]         = -inv;
        c[16 + a]    = 2.0f * inv * m;
        c[32 + a]    = rho[r * (NFEAT + 1) + a];
        K            = fmaf(-inv * m, m, K);
    }
    c[48] = rho[r * (NFEAT + 1) + NFEAT];
    c[49] = K;
}

__global__ __launch_bounds__(256) void fuzzy_main(const float* __restrict__ x,
                                                  const float* __restrict__ cst,
                                                  float* __restrict__ out,
                                                  int n) {
    int k = blockIdx.x * blockDim.x + threadIdx.x;
    if (k >= n) return;

    // Load this sample's 16 features (4 x float4, 64B per thread).
    const float4* x4 = (const float4*)(x + (size_t)k * NFEAT);
    float4 v0 = x4[0], v1 = x4[1], v2 = x4[2], v3 = x4[3];
    float xs[NFEAT] = {v0.x, v0.y, v0.z, v0.w,
                       v1.x, v1.y, v1.z, v1.w,
                       v2.x, v2.y, v2.z, v2.w,
                       v3.x, v3.y, v3.z, v3.w};
    float xq[NFEAT];
#pragma unroll
    for (int a = 0; a < NFEAT; ++a) xq[a] = xs[a] * xs[a];

    float num = 0.0f, den = 0.0f;
#pragma unroll 4
    for (int r = 0; r < NRULE; ++r) {
        const float* c = cst + r * RSTRIDE;   // wave-uniform -> s_load
        float z = c[48];
        float l = c[49];
#pragma unroll
        for (int a = 0; a < NFEAT; ++a) {
            z = fmaf(c[32 + a], xs[a], z);
            l = fmaf(c[a],      xq[a], l);
            l = fmaf(c[16 + a], xs[a], l);
        }
        float w = expf(l);       // logw <= ~0; underflows to 0 like the ref
        num = fmaf(z, w, num);
        den += w;
    }
    out[k] = num / (den + 1e-13f);
}

extern "C" void kernel_launch(void* const* d_in, const int* in_sizes, int n_in,
                              void* d_out, int out_size, void* d_ws, size_t ws_size,
                              hipStream_t stream) {
    const float* x     = (const float*)d_in[0];   // [N,16]
    const float* mu    = (const float*)d_in[1];   // [64,16]
    const float* sigma = (const float*)d_in[2];   // [64,16]
    const float* rho   = (const float*)d_in[3];   // [64,17]
    float* out = (float*)d_out;
    float* cst = (float*)d_ws;                    // 64*64*4 = 16 KB scratch

    int n = in_sizes[0] / NFEAT;                  // 131072

    fuzzy_prep<<<1, 64, 0, stream>>>(mu, sigma, rho, cst);
    fuzzy_main<<<(n + 255) / 256, 256, 0, stream>>>(x, cst, out, n);
}